// Round 9
// baseline (104.065 us; speedup 1.0000x reference)
//
#include <hip/hip_runtime.h>
#include <hip/hip_bf16.h>
#include <math.h>

// ProxyMLS: score = -0.5*(e2@iv^T - 2*e@(mu*iv)^T + const_j)
// pos_e = -32*(score-0.1) = 16*raw + (16*const_j + 3.2);  neg_e = 6.4 - pe
// R9: 3 nodes. k_prep deleted — k_main compute-stages its own A/B tiles
// from raw inputs straight into the swizzled LDS layout (ds_write_b128,
// 8 lanes/4-bank-group = b128 minimum, conflict-free) and computes pc
// in-block. Inputs (5 MB) are L2/L3-resident so the 32x/64x re-read
// redundancy is cheap. GEMM/epilogue/k_red1/k_fin identical to R8.

#define N_EMB 4096
#define C_CLS 8192
#define D_DIM 64
#define K_DIM 128   // concat [e^2 | e] x [iv | -2*mu*iv]

typedef __attribute__((ext_vector_type(8))) __bf16 bf16x8;
typedef __attribute__((ext_vector_type(16))) float f32x16;
typedef __attribute__((ext_vector_type(4))) int i32x4;

// 128x128 tile per block: compute-staged bf16 32x32x16 MFMA GEMM (K=128)
// + fused per-column online max / masked exp-sums. Partials -> ws[rb][gcol].
//
// LDS layout: tile = 128 rows x 16 chunks (16 B each), row stride 256 B.
// Slot (r, cs) holds GLOBAL chunk (r, cs ^ (r & 15)). Reader of chunk c of
// row r loads slot c ^ (r & 15); bank group = (c ^ (r&15)) & 7 -> 2 lanes
// per 4-bank group per 16-lane quarter -> conflict-free (m136).
__global__ __launch_bounds__(256, 2) void k_main(
    const float* __restrict__ emb, const float* __restrict__ mp,
    const float* __restrict__ lvp, const int* __restrict__ labels,
    float* __restrict__ wsM, float* __restrict__ wsP, float* __restrict__ wsN) {
  __shared__ __align__(16) char As[32768];  // 32 KB
  __shared__ __align__(16) char Bs[32768];  // 32 KB
  __shared__ float pc_s[128];               // 0.5 KB (65 KB -> 2 blocks/CU)

  const int tid = threadIdx.x;
  const int rb = blockIdx.x & 31;   // row block (N/128 = 32)
  const int cb = blockIdx.x >> 5;   // col block (C/128 = 64)

  // ---- A tile: [e^2 | e] bf16, swizzled. 1024 input-chunks of 8 d's. ----
  #pragma unroll
  for (int i = 0; i < 4; ++i) {
    int q = i * 256 + tid;
    int r = q >> 3, dc = q & 7;             // row-local, d-chunk (8 floats)
    const float* src = emb + (size_t)(rb * 128 + r) * D_DIM + dc * 8;
    float4 a = *(const float4*)src;
    float4 b = *(const float4*)(src + 4);
    bf16x8 sq = {(__bf16)(a.x*a.x), (__bf16)(a.y*a.y), (__bf16)(a.z*a.z),
                 (__bf16)(a.w*a.w), (__bf16)(b.x*b.x), (__bf16)(b.y*b.y),
                 (__bf16)(b.z*b.z), (__bf16)(b.w*b.w)};
    bf16x8 ev = {(__bf16)a.x, (__bf16)a.y, (__bf16)a.z, (__bf16)a.w,
                 (__bf16)b.x, (__bf16)b.y, (__bf16)b.z, (__bf16)b.w};
    int s1 = dc ^ (r & 15);                 // e^2 chunk c_g = dc
    *(bf16x8*)(As + r * 256 + s1 * 16) = sq;
    *(bf16x8*)(As + r * 256 + (s1 ^ 8) * 16) = ev;  // e chunk c_g = dc+8
  }
  // ---- B tile: [iv | -2*mu*iv] bf16, swizzled; pc_s per column. ----
  #pragma unroll
  for (int i = 0; i < 4; ++i) {
    int q = i * 256 + tid;
    int c = q >> 3, dc = q & 7;             // col-local, d-chunk
    const float* mus = mp + (size_t)(cb * 128 + c) * D_DIM + dc * 8;
    const float* lvs = lvp + (size_t)(cb * 128 + c) * D_DIM + dc * 8;
    float4 m0 = *(const float4*)mus, m1 = *(const float4*)(mus + 4);
    float4 l0 = *(const float4*)lvs, l1 = *(const float4*)(lvs + 4);
    float iv0 = __expf(-l0.x), iv1 = __expf(-l0.y);
    float iv2 = __expf(-l0.z), iv3 = __expf(-l0.w);
    float iv4 = __expf(-l1.x), iv5 = __expf(-l1.y);
    float iv6 = __expf(-l1.z), iv7 = __expf(-l1.w);
    bf16x8 ivv = {(__bf16)iv0, (__bf16)iv1, (__bf16)iv2, (__bf16)iv3,
                  (__bf16)iv4, (__bf16)iv5, (__bf16)iv6, (__bf16)iv7};
    bf16x8 mv = {(__bf16)(-2.0f*m0.x*iv0), (__bf16)(-2.0f*m0.y*iv1),
                 (__bf16)(-2.0f*m0.z*iv2), (__bf16)(-2.0f*m0.w*iv3),
                 (__bf16)(-2.0f*m1.x*iv4), (__bf16)(-2.0f*m1.y*iv5),
                 (__bf16)(-2.0f*m1.z*iv6), (__bf16)(-2.0f*m1.w*iv7)};
    int s1 = dc ^ (c & 15);
    *(bf16x8*)(Bs + c * 256 + s1 * 16) = ivv;
    *(bf16x8*)(Bs + c * 256 + (s1 ^ 8) * 16) = mv;
    // const_j partial over this thread's 8 d's; 8-lane group = one column
    float t = fmaf(m0.x*m0.x, iv0, l0.x) + fmaf(m0.y*m0.y, iv1, l0.y)
            + fmaf(m0.z*m0.z, iv2, l0.z) + fmaf(m0.w*m0.w, iv3, l0.w)
            + fmaf(m1.x*m1.x, iv4, l1.x) + fmaf(m1.y*m1.y, iv5, l1.y)
            + fmaf(m1.z*m1.z, iv6, l1.z) + fmaf(m1.w*m1.w, iv7, l1.w);
    t += __shfl_xor(t, 1); t += __shfl_xor(t, 2); t += __shfl_xor(t, 4);
    if (dc == 0) pc_s[c] = fmaf(16.0f, t, 3.2f);  // 16*const + alpha*margin
  }
  __syncthreads();

  const int wv = tid >> 6, lane = tid & 63;
  const int wr = wv >> 1, wc = wv & 1;   // 2x2 wave grid, 64x64 per wave
  const int l31 = lane & 31, kg = lane >> 5;  // A/B frag: row=l31, k=kg*8+j
  const int l15 = lane & 15;

  f32x16 acc[2][2];
  #pragma unroll
  for (int mi = 0; mi < 2; ++mi)
    #pragma unroll
    for (int ni = 0; ni < 2; ++ni)
      #pragma unroll
      for (int r = 0; r < 16; ++r) acc[mi][ni][r] = 0.f;

  #pragma unroll
  for (int kk = 0; kk < 8; ++kk) {       // K = 8 steps of 16
    const int c = kk * 2 + kg;           // wanted 16B K-chunk
    const int cofs = (c ^ l15) << 4;     // swizzled byte offset (row&15==l15)
    bf16x8 af[2], bfr[2];
    #pragma unroll
    for (int mi = 0; mi < 2; ++mi)
      af[mi] = *(const bf16x8*)(As + (wr * 64 + mi * 32 + l31) * 256 + cofs);
    #pragma unroll
    for (int ni = 0; ni < 2; ++ni)
      bfr[ni] = *(const bf16x8*)(Bs + (wc * 64 + ni * 32 + l31) * 256 + cofs);
    #pragma unroll
    for (int mi = 0; mi < 2; ++mi)
      #pragma unroll
      for (int ni = 0; ni < 2; ++ni)
        acc[mi][ni] = __builtin_amdgcn_mfma_f32_32x32x16_bf16(
            af[mi], bfr[ni], acc[mi][ni], 0, 0, 0);
  }

  __syncthreads();  // As/Bs dead; alias epilogue scratch onto As
  float* colred = (float*)As;  // [2][128][3] floats = 3072 B

  // C/D layout (32x32, m74/m101): col = lane&31, row = (reg&3)+8*(reg>>2)+4*kg.
  i32x4 labv[2][4];  // rows base+{0..3}, base = mi*32 + 4*kg + 8*g
  #pragma unroll
  for (int mi = 0; mi < 2; ++mi)
    #pragma unroll
    for (int g = 0; g < 4; ++g)
      labv[mi][g] = *(const i32x4*)&labels[rb * 128 + wr * 64 + mi * 32 + 4 * kg + 8 * g];

  #pragma unroll
  for (int ni = 0; ni < 2; ++ni) {
    const int col_local = wc * 64 + ni * 32 + l31;
    const int gcol = cb * 128 + col_local;
    const float pcv = pc_s[col_local];
    float lmax = -1e30f;
    #pragma unroll
    for (int mi = 0; mi < 2; ++mi)
      #pragma unroll
      for (int r = 0; r < 16; ++r)
        lmax = fmaxf(lmax, fmaf(16.0f, acc[mi][ni][r], pcv));
    lmax = fmaxf(lmax, __shfl_xor(lmax, 32));  // other kg half covers other rows
    float ps = 0.f, ns = 0.f;
    #pragma unroll
    for (int mi = 0; mi < 2; ++mi)
      #pragma unroll
      for (int r = 0; r < 16; ++r) {
        float pe = fmaf(16.0f, acc[mi][ni][r], pcv);
        bool match = (labv[mi][r >> 2][r & 3] == gcol);
        float v = match ? pe : (6.4f - pe);   // neg_e = 2*alpha*margin - pos_e
        float ex = __expf(v - lmax);
        ps += match ? ex : 0.f;
        ns += match ? 0.f : ex;
      }
    ps += __shfl_xor(ps, 32);
    ns += __shfl_xor(ns, 32);
    if (kg == 0) {
      float* cr = &colred[(wr * 128 + col_local) * 3];
      cr[0] = lmax; cr[1] = ps; cr[2] = ns;
    }
  }
  __syncthreads();
  if (tid < 128) {  // merge the two row-halves, write block partials
    const float* c0 = &colred[(0 * 128 + tid) * 3];
    const float* c1 = &colred[(1 * 128 + tid) * 3];
    float M = fmaxf(c0[0], c1[0]);
    float s0 = __expf(c0[0] - M), s1 = __expf(c1[0] - M);
    int gcol = cb * 128 + tid;
    wsM[rb * C_CLS + gcol] = M;
    wsP[rb * C_CLS + gcol] = fmaf(c0[1], s0, c1[1] * s1);
    wsN[rb * C_CLS + gcol] = fmaf(c0[2], s0, c1[2] * s1);
  }
}

// Reduction stage 1: 128 blocks x 256 thr. Block = 64 columns; part=tid>>6
// covers 8 of 32 row-blocks (8-reg M array, no spill). LDS merge across
// parts. No fences/atomics — inter-dispatch visibility is the runtime's job.
__global__ __launch_bounds__(256) void k_red1(
    const float* __restrict__ wsM, const float* __restrict__ wsP,
    const float* __restrict__ wsN, float* __restrict__ Mcol,
    float* __restrict__ Pcol, float* __restrict__ Ncol) {
  __shared__ float red[4][64][3];  // 3 KB
  const int tid = threadIdx.x;
  const int col = tid & 63, part = tid >> 6;   // 4 parts x 8 rb each
  const int j = blockIdx.x * 64 + col;

  float m8[8];
  float M = -1e30f;
  #pragma unroll
  for (int r = 0; r < 8; ++r) {
    m8[r] = wsM[(part * 8 + r) * C_CLS + j];
    M = fmaxf(M, m8[r]);
  }
  float ps = 0.f, ns = 0.f;
  #pragma unroll
  for (int r = 0; r < 8; ++r) {
    float s = __expf(m8[r] - M);
    ps = fmaf(wsP[(part * 8 + r) * C_CLS + j], s, ps);
    ns = fmaf(wsN[(part * 8 + r) * C_CLS + j], s, ns);
  }
  red[part][col][0] = M; red[part][col][1] = ps; red[part][col][2] = ns;
  __syncthreads();
  if (part == 0) {
    float M0 = red[0][col][0], M1 = red[1][col][0];
    float M2 = red[2][col][0], M3 = red[3][col][0];
    float Mx = fmaxf(fmaxf(M0, M1), fmaxf(M2, M3));
    float s0 = __expf(M0 - Mx), s1 = __expf(M1 - Mx);
    float s2 = __expf(M2 - Mx), s3 = __expf(M3 - Mx);
    Mcol[j] = Mx;
    Pcol[j] = fmaf(red[0][col][1], s0, fmaf(red[1][col][1], s1,
              fmaf(red[2][col][1], s2, red[3][col][1] * s3)));
    Ncol[j] = fmaf(red[0][col][2], s0, fmaf(red[1][col][2], s1,
              fmaf(red[2][col][2], s2, red[3][col][2] * s3)));
  }
}

// Final: single block x 1024 threads — global m, num_valid, log1p sums.
__global__ __launch_bounds__(1024) void k_fin(
    const float* __restrict__ Mcol, const float* __restrict__ Pcol,
    const float* __restrict__ Ncol, const int* __restrict__ labels,
    float* __restrict__ out) {
  __shared__ unsigned char flag[C_CLS];  // 8 KB
  __shared__ float sA[16], sB[16];
  __shared__ int sI[16];
  const int tid = threadIdx.x;
  const int wv = tid >> 6, lane = tid & 63;
  for (int i = tid; i < C_CLS; i += 1024) flag[i] = 0;
  __syncthreads();
  for (int i = tid; i < N_EMB; i += 1024) flag[labels[i]] = 1;
  __syncthreads();
  int nv = 0;
  float gm = -1e30f;
  #pragma unroll
  for (int k = 0; k < C_CLS / 1024; ++k) {
    int i = k * 1024 + tid;
    nv += flag[i];
    gm = fmaxf(gm, Mcol[i]);
  }
  #pragma unroll
  for (int s = 32; s >= 1; s >>= 1) {
    gm = fmaxf(gm, __shfl_xor(gm, s));
    nv += __shfl_xor(nv, s);
  }
  if (lane == 0) { sA[wv] = gm; sI[wv] = nv; }
  __syncthreads();
  if (tid == 0) {
    float mm = -1e30f; int n = 0;
    #pragma unroll
    for (int k = 0; k < 16; ++k) { mm = fmaxf(mm, sA[k]); n += sI[k]; }
    sA[0] = mm; sI[0] = n;
  }
  __syncthreads();
  const float m = sA[0];
  const int num_valid = sI[0];
  __syncthreads();
  float pt = 0.f, nt = 0.f;
  #pragma unroll
  for (int k = 0; k < C_CLS / 1024; ++k) {
    int i = k * 1024 + tid;
    float s = __expf(Mcol[i] - m);
    pt += log1pf(Pcol[i] * s);
    nt += log1pf(Ncol[i] * s);
  }
  #pragma unroll
  for (int s = 32; s >= 1; s >>= 1) {
    pt += __shfl_xor(pt, s);
    nt += __shfl_xor(nt, s);
  }
  if (lane == 0) { sA[wv] = pt; sB[wv] = nt; }
  __syncthreads();
  if (tid == 0) {
    float sp = 0.f, sn = 0.f;
    #pragma unroll
    for (int k = 0; k < 16; ++k) { sp += sA[k]; sn += sB[k]; }
    out[0] = (sp + (float)C_CLS * m) / (float)num_valid
           + (sn + (float)C_CLS * m) / (float)C_CLS;
  }
}

extern "C" void kernel_launch(void* const* d_in, const int* in_sizes, int n_in,
                              void* d_out, int out_size, void* d_ws, size_t ws_size,
                              hipStream_t stream) {
  const float* emb    = (const float*)d_in[0];
  const int*   labels = (const int*)d_in[1];
  const float* mp     = (const float*)d_in[2];
  const float* lvp    = (const float*)d_in[3];
  float* out = (float*)d_out;

  char* ws = (char*)d_ws;
  float* wsM  = (float*)ws;          // 32*8192*4 = 1 MB
  float* wsP  = wsM + 32 * C_CLS;    // 1 MB
  float* wsN  = wsP + 32 * C_CLS;    // 1 MB
  float* Mcol = wsN + 32 * C_CLS;    // 32 KB
  float* Pcol = Mcol + C_CLS;        // 32 KB
  float* Ncol = Pcol + C_CLS;        // 32 KB

  hipLaunchKernelGGL(k_main, dim3((N_EMB / 128) * (C_CLS / 128)), dim3(256), 0, stream,
                     emb, mp, lvp, labels, wsM, wsP, wsN);
  hipLaunchKernelGGL(k_red1, dim3(128), dim3(256), 0, stream,
                     wsM, wsP, wsN, Mcol, Pcol, Ncol);
  hipLaunchKernelGGL(k_fin, dim3(1), dim3(1024), 0, stream,
                     Mcol, Pcol, Ncol, labels, out);
}

// Round 10
// 101.582 us; speedup vs baseline: 1.0244x; 1.0244x over previous
//
#include <hip/hip_runtime.h>
#include <hip/hip_bf16.h>
#include <math.h>

// ProxyMLS: score = -0.5*(e2@iv^T - 2*e@(mu*iv)^T + const_j)
// pos_e = -32*(score-0.1) = 16*raw + (16*const_j + 3.2);  neg_e = 6.4 - pos_e
// R10: revert to R8 (best measured 102.0/102.1 twice; all 3-node variants
// R6/R7/R9 = ~104) + two latency tweaks: k_red1 at 256 blocks (all CUs),
// k_fin hoists its 24 global loads above the flag phase.

#define N_EMB 4096
#define C_CLS 8192
#define D_DIM 64
#define K_DIM 128   // concat [e^2 | e] x [iv | -2*mu*iv]

typedef __attribute__((ext_vector_type(8))) __bf16 bf16x8;
typedef __attribute__((ext_vector_type(4))) __bf16 bf16x4;
typedef __attribute__((ext_vector_type(16))) float f32x16;
typedef __attribute__((ext_vector_type(4))) int i32x4;

__device__ __forceinline__ void async_ld16(void* lds, const void* g) {
  __builtin_amdgcn_global_load_lds(
      (__attribute__((address_space(1))) void*)g,
      (__attribute__((address_space(3))) void*)lds, 16, 0, 0);
}

// Vectorized prep: wave handles 4 rows; lane = (sub=lane>>4 row, q=lane&15
// covering d = q*4..q*4+3 via float4). A=[e^2|e], B=[iv|-2*mu*iv],
// const_j = sum_d(mu^2*iv + logvar) via 16-lane xor-shuffle reduce.
__global__ void k_prep(const float* __restrict__ emb,
                       const float* __restrict__ mp,
                       const float* __restrict__ lvp,
                       __bf16* __restrict__ wsA,
                       __bf16* __restrict__ wsB,
                       float* __restrict__ constv) {
  const int wave = (int)((blockIdx.x * blockDim.x + threadIdx.x) >> 6);
  const int lane = threadIdx.x & 63;
  const int sub = lane >> 4, q = lane & 15;
  const int row = wave * 4 + sub;   // 12288 rows total
  if (row < N_EMB) {
    float4 e4 = *(const float4*)&emb[row * D_DIM + q * 4];
    bf16x4 sq = {(__bf16)(e4.x * e4.x), (__bf16)(e4.y * e4.y),
                 (__bf16)(e4.z * e4.z), (__bf16)(e4.w * e4.w)};
    bf16x4 ev = {(__bf16)e4.x, (__bf16)e4.y, (__bf16)e4.z, (__bf16)e4.w};
    *(bf16x4*)&wsA[row * K_DIM + q * 4] = sq;
    *(bf16x4*)&wsA[row * K_DIM + D_DIM + q * 4] = ev;
  } else {
    const int j = row - N_EMB;
    float4 mu4 = *(const float4*)&mp[j * D_DIM + q * 4];
    float4 lv4 = *(const float4*)&lvp[j * D_DIM + q * 4];
    float iv0 = __expf(-lv4.x), iv1 = __expf(-lv4.y);
    float iv2 = __expf(-lv4.z), iv3 = __expf(-lv4.w);
    bf16x4 ivv = {(__bf16)iv0, (__bf16)iv1, (__bf16)iv2, (__bf16)iv3};
    bf16x4 mv = {(__bf16)(-2.0f * mu4.x * iv0), (__bf16)(-2.0f * mu4.y * iv1),
                 (__bf16)(-2.0f * mu4.z * iv2), (__bf16)(-2.0f * mu4.w * iv3)};
    *(bf16x4*)&wsB[j * K_DIM + q * 4] = ivv;
    *(bf16x4*)&wsB[j * K_DIM + D_DIM + q * 4] = mv;
    float t = fmaf(mu4.x * mu4.x, iv0, lv4.x)
            + fmaf(mu4.y * mu4.y, iv1, lv4.y)
            + fmaf(mu4.z * mu4.z, iv2, lv4.z)
            + fmaf(mu4.w * mu4.w, iv3, lv4.w);
    #pragma unroll
    for (int s = 8; s >= 1; s >>= 1) t += __shfl_xor(t, s);  // within 16-group
    if (q == 0) constv[j] = t;
  }
}

// 128x128 tile per block: bf16 32x32x16 MFMA GEMM (K=128) + fused per-column
// online max / masked exp-sums. Partials -> ws[rb][gcol].
//
// LDS layout: tile = 128 rows x 16 chunks (16 B each), row stride 256 B.
// Slot (r, cs) holds GLOBAL chunk (r, cs ^ (r & 15)). Reader of chunk c of
// row r loads slot c ^ (r & 15); bank group = (c ^ (r&15)) & 7 -> 2 lanes
// per 4-bank group per 16-lane quarter -> conflict-free (m136).
__global__ __launch_bounds__(256, 2) void k_main(
    const __bf16* __restrict__ wsA, const __bf16* __restrict__ wsB,
    const float* __restrict__ constv, const int* __restrict__ labels,
    float* __restrict__ wsM, float* __restrict__ wsP, float* __restrict__ wsN) {
  __shared__ __align__(16) char As[32768];  // 32 KB
  __shared__ __align__(16) char Bs[32768];  // 32 KB  (64 KB -> 2 blocks/CU)

  const int tid = threadIdx.x;
  const int rb = blockIdx.x & 31;   // row block (N/128 = 32)
  const int cb = blockIdx.x >> 5;   // col block (C/128 = 64)

  const char* Ag = (const char*)(wsA + (size_t)rb * 128 * K_DIM);
  const char* Bg = (const char*)(wsB + (size_t)cb * 128 * K_DIM);
  #pragma unroll
  for (int it = 0; it < 8; ++it) {
    int L = it * 256 + tid;
    int r = L >> 4, cs = L & 15;
    int goff = r * 256 + ((cs ^ (r & 15)) << 4);
    async_ld16(As + L * 16, Ag + goff);
  }
  #pragma unroll
  for (int it = 0; it < 8; ++it) {
    int L = it * 256 + tid;
    int r = L >> 4, cs = L & 15;
    int goff = r * 256 + ((cs ^ (r & 15)) << 4);
    async_ld16(Bs + L * 16, Bg + goff);
  }
  __syncthreads();  // drains vmcnt before barrier

  const int wv = tid >> 6, lane = tid & 63;
  const int wr = wv >> 1, wc = wv & 1;   // 2x2 wave grid, 64x64 per wave
  const int l31 = lane & 31, kg = lane >> 5;  // A/B frag: row=l31, k=kg*8+j
  const int l15 = lane & 15;

  f32x16 acc[2][2];
  #pragma unroll
  for (int mi = 0; mi < 2; ++mi)
    #pragma unroll
    for (int ni = 0; ni < 2; ++ni)
      #pragma unroll
      for (int r = 0; r < 16; ++r) acc[mi][ni][r] = 0.f;

  #pragma unroll
  for (int kk = 0; kk < 8; ++kk) {       // K = 8 steps of 16
    const int c = kk * 2 + kg;           // wanted 16B K-chunk
    const int cofs = (c ^ l15) << 4;     // swizzled byte offset (row&15==l15)
    bf16x8 af[2], bfr[2];
    #pragma unroll
    for (int mi = 0; mi < 2; ++mi)
      af[mi] = *(const bf16x8*)(As + (wr * 64 + mi * 32 + l31) * 256 + cofs);
    #pragma unroll
    for (int ni = 0; ni < 2; ++ni)
      bfr[ni] = *(const bf16x8*)(Bs + (wc * 64 + ni * 32 + l31) * 256 + cofs);
    #pragma unroll
    for (int mi = 0; mi < 2; ++mi)
      #pragma unroll
      for (int ni = 0; ni < 2; ++ni)
        acc[mi][ni] = __builtin_amdgcn_mfma_f32_32x32x16_bf16(
            af[mi], bfr[ni], acc[mi][ni], 0, 0, 0);
  }

  __syncthreads();  // As/Bs dead; alias epilogue scratch onto As
  float* colred = (float*)As;         // [2][128][3] floats = 3072 B
  int* labels_s = (int*)(As + 3072);  // 512 B (16B-aligned)
  float* pc_s   = (float*)(As + 3584);// 512 B
  if (tid < 128) {
    labels_s[tid] = labels[rb * 128 + tid];
    pc_s[tid] = fmaf(16.0f, constv[cb * 128 + tid], 3.2f);  // 16*const+alpha*margin
  }
  __syncthreads();

  // C/D layout (32x32, m74/m101): col = lane&31, row = (reg&3)+8*(reg>>2)+4*kg.
  i32x4 labv[2][4];  // labv[mi][g] = labels of rows base+{0..3}, base=mi*32+4*kg+8*g
  #pragma unroll
  for (int mi = 0; mi < 2; ++mi)
    #pragma unroll
    for (int g = 0; g < 4; ++g)
      labv[mi][g] = *(const i32x4*)&labels_s[wr * 64 + mi * 32 + 4 * kg + 8 * g];

  #pragma unroll
  for (int ni = 0; ni < 2; ++ni) {
    const int col_local = wc * 64 + ni * 32 + l31;
    const int gcol = cb * 128 + col_local;
    const float pcv = pc_s[col_local];
    float lmax = -1e30f;
    #pragma unroll
    for (int mi = 0; mi < 2; ++mi)
      #pragma unroll
      for (int r = 0; r < 16; ++r)
        lmax = fmaxf(lmax, fmaf(16.0f, acc[mi][ni][r], pcv));
    lmax = fmaxf(lmax, __shfl_xor(lmax, 32));  // other kg half covers other rows
    float ps = 0.f, ns = 0.f;
    #pragma unroll
    for (int mi = 0; mi < 2; ++mi)
      #pragma unroll
      for (int r = 0; r < 16; ++r) {
        float pe = fmaf(16.0f, acc[mi][ni][r], pcv);
        bool match = (labv[mi][r >> 2][r & 3] == gcol);
        float v = match ? pe : (6.4f - pe);   // neg_e = 2*alpha*margin - pos_e
        float ex = __expf(v - lmax);
        ps += match ? ex : 0.f;
        ns += match ? 0.f : ex;
      }
    ps += __shfl_xor(ps, 32);
    ns += __shfl_xor(ns, 32);
    if (kg == 0) {
      float* cr = &colred[(wr * 128 + col_local) * 3];
      cr[0] = lmax; cr[1] = ps; cr[2] = ns;
    }
  }
  __syncthreads();
  if (tid < 128) {  // merge the two row-halves, write block partials
    const float* c0 = &colred[(0 * 128 + tid) * 3];
    const float* c1 = &colred[(1 * 128 + tid) * 3];
    float M = fmaxf(c0[0], c1[0]);
    float s0 = __expf(c0[0] - M), s1 = __expf(c1[0] - M);
    int gcol = cb * 128 + tid;
    wsM[rb * C_CLS + gcol] = M;
    wsP[rb * C_CLS + gcol] = fmaf(c0[1], s0, c1[1] * s1);
    wsN[rb * C_CLS + gcol] = fmaf(c0[2], s0, c1[2] * s1);
  }
}

// Reduction stage 1: 256 blocks x 256 thr (one block per CU). Block =
// 32 columns; part=tid>>5 covers 4 of 32 row-blocks. LDS merge across
// 8 parts. No fences/atomics.
__global__ __launch_bounds__(256) void k_red1(
    const float* __restrict__ wsM, const float* __restrict__ wsP,
    const float* __restrict__ wsN, float* __restrict__ Mcol,
    float* __restrict__ Pcol, float* __restrict__ Ncol) {
  __shared__ float red[8][32][3];  // 3 KB
  const int tid = threadIdx.x;
  const int col = tid & 31, part = tid >> 5;   // 8 parts x 4 rb each
  const int j = blockIdx.x * 32 + col;

  float m4[4];
  float M = -1e30f;
  #pragma unroll
  for (int r = 0; r < 4; ++r) {
    m4[r] = wsM[(part * 4 + r) * C_CLS + j];
    M = fmaxf(M, m4[r]);
  }
  float ps = 0.f, ns = 0.f;
  #pragma unroll
  for (int r = 0; r < 4; ++r) {
    float s = __expf(m4[r] - M);
    ps = fmaf(wsP[(part * 4 + r) * C_CLS + j], s, ps);
    ns = fmaf(wsN[(part * 4 + r) * C_CLS + j], s, ns);
  }
  red[part][col][0] = M; red[part][col][1] = ps; red[part][col][2] = ns;
  __syncthreads();
  if (part == 0) {
    float Mx = -1e30f;
    #pragma unroll
    for (int p = 0; p < 8; ++p) Mx = fmaxf(Mx, red[p][col][0]);
    float P = 0.f, Nn = 0.f;
    #pragma unroll
    for (int p = 0; p < 8; ++p) {
      float s = __expf(red[p][col][0] - Mx);
      P = fmaf(red[p][col][1], s, P);
      Nn = fmaf(red[p][col][2], s, Nn);
    }
    Mcol[j] = Mx; Pcol[j] = P; Ncol[j] = Nn;
  }
}

// Final: single block x 1024 threads — global m, num_valid, log1p sums.
// All 24 global loads hoisted above the flag phase to hide their latency.
__global__ __launch_bounds__(1024) void k_fin(
    const float* __restrict__ Mcol, const float* __restrict__ Pcol,
    const float* __restrict__ Ncol, const int* __restrict__ labels,
    float* __restrict__ out) {
  __shared__ unsigned char flag[C_CLS];  // 8 KB
  __shared__ float sA[16], sB[16];
  __shared__ int sI[16];
  const int tid = threadIdx.x;
  const int wv = tid >> 6, lane = tid & 63;

  float colMv[8], colPv[8], colNv[8];
  #pragma unroll
  for (int k = 0; k < 8; ++k) {
    int i = k * 1024 + tid;
    colMv[k] = Mcol[i]; colPv[k] = Pcol[i]; colNv[k] = Ncol[i];
  }

  for (int i = tid; i < C_CLS; i += 1024) flag[i] = 0;
  __syncthreads();
  for (int i = tid; i < N_EMB; i += 1024) flag[labels[i]] = 1;
  __syncthreads();
  int nv = 0;
  float gm = -1e30f;
  #pragma unroll
  for (int k = 0; k < 8; ++k) {
    nv += flag[k * 1024 + tid];
    gm = fmaxf(gm, colMv[k]);
  }
  #pragma unroll
  for (int s = 32; s >= 1; s >>= 1) {
    gm = fmaxf(gm, __shfl_xor(gm, s));
    nv += __shfl_xor(nv, s);
  }
  if (lane == 0) { sA[wv] = gm; sI[wv] = nv; }
  __syncthreads();
  if (tid == 0) {
    float mm = -1e30f; int n = 0;
    #pragma unroll
    for (int k = 0; k < 16; ++k) { mm = fmaxf(mm, sA[k]); n += sI[k]; }
    sA[0] = mm; sI[0] = n;
  }
  __syncthreads();
  const float m = sA[0];
  const int num_valid = sI[0];
  __syncthreads();
  float pt = 0.f, nt = 0.f;
  #pragma unroll
  for (int k = 0; k < 8; ++k) {
    float s = __expf(colMv[k] - m);
    pt += log1pf(colPv[k] * s);
    nt += log1pf(colNv[k] * s);
  }
  #pragma unroll
  for (int s = 32; s >= 1; s >>= 1) {
    pt += __shfl_xor(pt, s);
    nt += __shfl_xor(nt, s);
  }
  if (lane == 0) { sA[wv] = pt; sB[wv] = nt; }
  __syncthreads();
  if (tid == 0) {
    float sp = 0.f, sn = 0.f;
    #pragma unroll
    for (int k = 0; k < 16; ++k) { sp += sA[k]; sn += sB[k]; }
    out[0] = (sp + (float)C_CLS * m) / (float)num_valid
           + (sn + (float)C_CLS * m) / (float)C_CLS;
  }
}

extern "C" void kernel_launch(void* const* d_in, const int* in_sizes, int n_in,
                              void* d_out, int out_size, void* d_ws, size_t ws_size,
                              hipStream_t stream) {
  const float* emb    = (const float*)d_in[0];
  const int*   labels = (const int*)d_in[1];
  const float* mp     = (const float*)d_in[2];
  const float* lvp    = (const float*)d_in[3];
  float* out = (float*)d_out;

  char* ws = (char*)d_ws;
  __bf16* wsA   = (__bf16*)ws;                            // 4096*128*2 = 1 MB
  __bf16* wsB   = (__bf16*)(ws + (1u << 20));             // 8192*128*2 = 2 MB
  float* constv = (float*)(ws + 3u * (1u << 20));         // 32 KB
  float* wsM    = (float*)(ws + 3u * (1u << 20) + (1u << 15));  // 32*8192*4 = 1 MB
  float* wsP    = wsM + 32 * C_CLS;                       // 1 MB
  float* wsN    = wsP + 32 * C_CLS;                       // 1 MB
  float* Mcol   = wsN + 32 * C_CLS;                       // 32 KB
  float* Pcol   = Mcol + C_CLS;                           // 32 KB
  float* Ncol   = Pcol + C_CLS;                           // 32 KB

  // 12288 rows / 4 rows-per-wave / 4 waves-per-block = 768 blocks
  hipLaunchKernelGGL(k_prep, dim3(768), dim3(256), 0, stream,
                     emb, mp, lvp, wsA, wsB, constv);
  hipLaunchKernelGGL(k_main, dim3((N_EMB / 128) * (C_CLS / 128)), dim3(256), 0, stream,
                     wsA, wsB, constv, labels, wsM, wsP, wsN);
  hipLaunchKernelGGL(k_red1, dim3(256), dim3(256), 0, stream,
                     wsM, wsP, wsN, Mcol, Pcol, Ncol);
  hipLaunchKernelGGL(k_fin, dim3(1), dim3(1024), 0, stream,
                     Mcol, Pcol, Ncol, labels, out);
}